// Round 5
// baseline (397.182 us; speedup 1.0000x reference)
//
#include <hip/hip_runtime.h>
#include <math.h>

// L=4096, N=16, H=16, E=64. rho-rows = L*N = 65536 (each 1024 floats, head h at +64h).
// out[rho][h][f] = exp2( x.Ps[h][:,f] - sq[rho]*SQS ) + 1e-6 with
//   Ps = proj * 64^-0.25 * log2(e), sq = sum(d^2), SQS = log2(e)/16.
// proj = q^T D of LAPACK-convention QR(pm[h]^T), D = sign(diag(r)) — convention-
// dependent (round-2 lesson): reproduce geqrf signs. Factor only; Q = M R^-1.

typedef float f32x2 __attribute__((ext_vector_type(2)));

#define BARLDS() do { asm volatile("s_waitcnt lgkmcnt(0)" ::: "memory"); \
                      __builtin_amdgcn_s_barrier();                      \
                      asm volatile("" ::: "memory"); } while (0)

#if __has_builtin(__builtin_amdgcn_exp2f)
#define EXP2F(x) __builtin_amdgcn_exp2f(x)
#else
#define EXP2F(x) exp2f(x)
#endif

static __device__ __forceinline__ f32x2 fma2(f32x2 a, f32x2 b, f32x2 c) {
    return __builtin_elementwise_fma(a, b, c);
}

// ------- per-head Householder factor (LAPACK signs) + solve, fp64, regs -----
__global__ __launch_bounds__(256) void qr_kernel(const float* __restrict__ pm,
                                                 float* __restrict__ P)
{
    __shared__ double S[4804];
    double* Rs    = S;          // 64*65 = 4160 (R rows)
    double* Ws    = S + 4160;   // 256 reduction partials
    double* colb  = S + 4416;   // 64 current column
    double* nrmb  = S + 4480;   // 4 partial norms
    double* betas = S + 4484;   // 64
    double* qcA   = S + 4548;   // 64
    double* qcB   = S + 4612;   // 64
    double* invb  = S + 4676;   // 64
    double* sgn   = S + 4740;   // 64

    const int tid = threadIdx.x;
    const int h   = blockIdx.x;
    const int c   = tid & 63;          // owned column
    const int q   = tid >> 6;          // row quarter
    const int i0  = q * 16;

    double A[16], M[16];
    #pragma unroll
    for (int k = 0; k < 16; ++k)
        A[k] = M[k] = (double)pm[h * 4096 + c * 64 + i0 + k];  // M[i][c]=pm[h][c][i]

    if (c == 0) {
        #pragma unroll
        for (int k = 0; k < 16; ++k) colb[i0 + k] = A[k];
        double np = 0.0;
        #pragma unroll
        for (int k = 0; k < 16; ++k) if (i0 + k >= 1) np = fma(A[k], A[k], np);
        nrmb[q] = np;
    }
    BARLDS();

    // ---- factor: A -> R (upper, in regs), 2 barriers/step ----
    #pragma unroll 1
    for (int j = 0; j < 64; ++j) {
        const double t     = (nrmb[0] + nrmb[1]) + (nrmb[2] + nrmb[3]);
        const double alpha = colb[j];
        double beta, tau, scale;
        if (t == 0.0) { beta = alpha; tau = 0.0; scale = 0.0; }
        else {
            const double an = sqrt(fma(alpha, alpha, t));
            beta  = (alpha >= 0.0) ? -an : an;     // -sign(alpha)*norm
            tau   = (beta - alpha) / beta;
            scale = 1.0 / (alpha - beta);
        }
        double v[16], w = 0.0;
        #pragma unroll
        for (int k = 0; k < 16; ++k) {
            const int i = i0 + k;
            v[k] = (i == j) ? 1.0 : ((i > j) ? colb[i] * scale : 0.0);
            w = fma(v[k], A[k], w);
        }
        Ws[q * 64 + c] = w;
        if (c == j && q == 0) betas[j] = beta;
        BARLDS();
        if (c > j) {
            const double tw = tau * ((Ws[c] + Ws[64 + c]) + (Ws[128 + c] + Ws[192 + c]));
            #pragma unroll
            for (int k = 0; k < 16; ++k) A[k] = fma(-tw, v[k], A[k]);
            if (c == j + 1) {                      // publish next column + norm
                #pragma unroll
                for (int k = 0; k < 16; ++k) colb[i0 + k] = A[k];
                double np = 0.0;
                #pragma unroll
                for (int k = 0; k < 16; ++k) if (i0 + k > j + 1) np = fma(A[k], A[k], np);
                nrmb[q] = np;
            }
        } else if (c == j) {
            #pragma unroll
            for (int k = 0; k < 16; ++k) if (i0 + k == j) A[k] = beta;
        }
        BARLDS();
    }

    // R rows to LDS; diag inverses; sign factors (fold 64^-0.25*log2e); q prologue
    #pragma unroll
    for (int k = 0; k < 16; ++k) Rs[(i0 + k) * 65 + c] = A[k];
    const double NZL2E = 0.35355339059327373 * 1.4426950408889634;
    if (tid < 64) {
        const double b = betas[tid];
        invb[tid] = 1.0 / b;
        sgn[tid]  = (b >= 0.0) ? NZL2E : -NZL2E;
    }
    if (c == 0) {
        #pragma unroll
        for (int k = 0; k < 16; ++k) qcA[i0 + k] = M[k];
    }
    BARLDS();

    // ---- solve Q R = M column sweep; write P[h][e=j][f=i] = Q[i][j]*sgn_i ----
    #pragma unroll 1
    for (int j = 0; j < 64; ++j) {
        double* qcur = (j & 1) ? qcB : qcA;
        double* qnxt = (j & 1) ? qcA : qcB;
        const double invd = invb[j];
        double qc[16];
        #pragma unroll
        for (int k = 0; k < 16; ++k) qc[k] = qcur[i0 + k];
        if (c == j) {
            #pragma unroll
            for (int k = 0; k < 16; ++k)
                P[h * 4096 + j * 64 + i0 + k] = (float)(qc[k] * invd * sgn[i0 + k]);
        }
        if (c > j) {
            const double f = Rs[j * 65 + c] * invd;
            #pragma unroll
            for (int k = 0; k < 16; ++k) M[k] = fma(-qc[k], f, M[k]);
            if (c == j + 1) {
                #pragma unroll
                for (int k = 0; k < 16; ++k) qnxt[i0 + k] = M[k];
            }
        }
        BARLDS();
    }
}

// ---------------- FAVOR+ map: x from global (L1), P from LDS ---------------
// thread = 4 rows x 8 features (4fi..4fi+3 and 32+4fi..). 8 lanes share each
// x address (dedup), sq computed inline from registers, pk-fma via f32x2.
#define ROW1(r, XS, J)                                   \
    do { const f32x2 xs = {XS, XS};                      \
         acc##r[0] = fma2(xs, pAlo[J], acc##r[0]);       \
         acc##r[1] = fma2(xs, pAhi[J], acc##r[1]);       \
         acc##r[2] = fma2(xs, pBlo[J], acc##r[2]);       \
         acc##r[3] = fma2(xs, pBhi[J], acc##r[3]); } while (0)

#define ROW4(r, XV)                                                           \
    do { sq[r] = fmaf(XV.w, XV.w, fmaf(XV.z, XV.z,                            \
                 fmaf(XV.y, XV.y, fmaf(XV.x, XV.x, sq[r]))));                 \
         ROW1(r, XV.x, 0); ROW1(r, XV.y, 1);                                  \
         ROW1(r, XV.z, 2); ROW1(r, XV.w, 3); } while (0)

__global__ __launch_bounds__(256) void favor_kernel(const float* __restrict__ data,
                                                    const float* __restrict__ P,
                                                    float* __restrict__ out)
{
    __shared__ float Ps[4096];          // Ps[e*64+f], pre-scaled by nz*log2e

    const int tid   = threadIdx.x;
    const int h     = blockIdx.x & 15;
    const int chunk = blockIdx.x >> 4;  // 0..63 -> 1024 rho-rows each

    #pragma unroll
    for (int k = 0; k < 4; ++k) {
        const int idx = tid + 256 * k;
        reinterpret_cast<float4*>(Ps)[idx] =
            reinterpret_cast<const float4*>(P)[h * 1024 + idx];
    }
    __syncthreads();

    const int fi = tid & 7;             // feature group
    const int ri = tid >> 3;            // 0..31 -> 4 rows each
    const float* pb = Ps + 4 * fi;
    const float SQS = 0.09016844005556021f;    // log2(e)/16

    const size_t rho0 = (size_t)chunk * 1024 + 4 * (size_t)ri;
    const float* __restrict__ dbase = data + (size_t)h * 64;
    float* __restrict__ obase = out + (size_t)h * 64 + 4 * fi;

    #pragma unroll 1
    for (int pass = 0; pass < 8; ++pass) {
        const size_t r0 = rho0 + 128 * (size_t)pass;
        const float* xp0 = dbase + (r0    ) * 1024;
        const float* xp1 = dbase + (r0 + 1) * 1024;
        const float* xp2 = dbase + (r0 + 2) * 1024;
        const float* xp3 = dbase + (r0 + 3) * 1024;

        f32x2 acc0[4], acc1[4], acc2[4], acc3[4];
        #pragma unroll
        for (int k = 0; k < 4; ++k) {
            acc0[k] = (f32x2){0.f, 0.f}; acc1[k] = (f32x2){0.f, 0.f};
            acc2[k] = (f32x2){0.f, 0.f}; acc3[k] = (f32x2){0.f, 0.f};
        }
        float sq[4] = {0.f, 0.f, 0.f, 0.f};

        #pragma unroll 2
        for (int e0 = 0; e0 < 64; e0 += 4) {
            const float4 xv0 = *reinterpret_cast<const float4*>(xp0 + e0);
            const float4 xv1 = *reinterpret_cast<const float4*>(xp1 + e0);
            const float4 xv2 = *reinterpret_cast<const float4*>(xp2 + e0);
            const float4 xv3 = *reinterpret_cast<const float4*>(xp3 + e0);
            f32x2 pAlo[4], pAhi[4], pBlo[4], pBhi[4];
            #pragma unroll
            for (int j = 0; j < 4; ++j) {
                const float4 a = *reinterpret_cast<const float4*>(pb + (e0 + j) * 64);
                const float4 b = *reinterpret_cast<const float4*>(pb + (e0 + j) * 64 + 32);
                pAlo[j] = (f32x2){a.x, a.y}; pAhi[j] = (f32x2){a.z, a.w};
                pBlo[j] = (f32x2){b.x, b.y}; pBhi[j] = (f32x2){b.z, b.w};
            }
            ROW4(0, xv0); ROW4(1, xv1); ROW4(2, xv2); ROW4(3, xv3);
        }

        // epilogue: exp2 + eps, coalesced float4 stores
        #pragma unroll
        for (int r = 0; r < 4; ++r) {
            const f32x2* ac = (r == 0) ? acc0 : (r == 1) ? acc1 : (r == 2) ? acc2 : acc3;
            const float s = sq[r] * SQS;
            float4 oA, oB;
            oA.x = EXP2F(ac[0][0] - s) + 1e-6f; oA.y = EXP2F(ac[0][1] - s) + 1e-6f;
            oA.z = EXP2F(ac[1][0] - s) + 1e-6f; oA.w = EXP2F(ac[1][1] - s) + 1e-6f;
            oB.x = EXP2F(ac[2][0] - s) + 1e-6f; oB.y = EXP2F(ac[2][1] - s) + 1e-6f;
            oB.z = EXP2F(ac[3][0] - s) + 1e-6f; oB.w = EXP2F(ac[3][1] - s) + 1e-6f;
            *reinterpret_cast<float4*>(obase + (r0 + r) * 1024)      = oA;
            *reinterpret_cast<float4*>(obase + (r0 + r) * 1024 + 32) = oB;
        }
    }
}

extern "C" void kernel_launch(void* const* d_in, const int* in_sizes, int n_in,
                              void* d_out, int out_size, void* d_ws, size_t ws_size,
                              hipStream_t stream)
{
    const float* data = (const float*)d_in[0];   // (L,N,H,E) fp32
    const float* pm   = (const float*)d_in[1];   // (H,E,E)   fp32
    float* out = (float*)d_out;                  // (L,N,H,F) fp32
    float* P   = (float*)d_ws;                   // 16*64*64*4 = 256 KB scratch

    qr_kernel<<<16, 256, 0, stream>>>(pm, P);
    favor_kernel<<<1024, 256, 0, stream>>>(data, P, out);
}

// Round 6
// 248.752 us; speedup vs baseline: 1.5967x; 1.5967x over previous
//
#include <hip/hip_runtime.h>
#include <math.h>

// L=4096, N=16, H=16, E=64. rho = L*N = 65536 rows of 1024 floats (head h at +64h).
// out[rho][h][f] = exp2( x.Ps[h][:,f] - sq*SQS ) + 1e-6, Ps = proj*64^-.25*log2e.
// proj = q^T D, D = sign(diag(r)) of LAPACK-convention QR(pm[h]^T) (convention-
// dependent — must reproduce geqrf signs; round-2 lesson). Factor then Q = M R^-1.

typedef float f32x2 __attribute__((ext_vector_type(2)));

#define AS1 __attribute__((address_space(1)))
#define AS3 __attribute__((address_space(3)))

#if __has_builtin(__builtin_amdgcn_exp2f)
#define EXP2F(x) __builtin_amdgcn_exp2f(x)
#else
#define EXP2F(x) exp2f(x)
#endif

static __device__ __forceinline__ void gload16(const float* g, float* l) {
    __builtin_amdgcn_global_load_lds((AS1 const void*)g, (AS3 void*)l, 16, 0, 0);
}
static __device__ __forceinline__ f32x2 fma2(f32x2 a, f32x2 b, f32x2 c) {
    return __builtin_elementwise_fma(a, b, c);
}

// ---------------- per-head QR: tid=4c+q, quad-shfl reduce, 1 barrier/step ----
__global__ __launch_bounds__(256) void qr_kernel(const float* __restrict__ pm,
                                                 float* __restrict__ P)
{
    __shared__ double colb[2][64];
    __shared__ double nrmb[2];
    __shared__ double Rs[64 * 65];
    __shared__ double qcol[2][64];
    __shared__ double dval[64];
    __shared__ double dinv[64];
    __shared__ double sgnNZ[64];

    const int tid = threadIdx.x;
    const int h   = blockIdx.x;
    const int c   = tid >> 2;       // column 0..63 (quad = 4 consecutive lanes)
    const int q   = tid & 3;        // row-quarter
    const int i0  = q * 16;

    double A[16], M[16];            // A[k] = M[i0+k][c] = pm[h][c][i0+k]
    {
        const float4* src = reinterpret_cast<const float4*>(pm + h * 4096 + c * 64 + i0);
        #pragma unroll
        for (int k4 = 0; k4 < 4; ++k4) {
            const float4 v = src[k4];
            A[4*k4+0] = M[4*k4+0] = (double)v.x;
            A[4*k4+1] = M[4*k4+1] = (double)v.y;
            A[4*k4+2] = M[4*k4+2] = (double)v.z;
            A[4*k4+3] = M[4*k4+3] = (double)v.w;
        }
    }
    if (c == 0) {                    // publish column 0 + its sub-norm
        #pragma unroll
        for (int k = 0; k < 16; ++k) colb[0][i0 + k] = A[k];
        double np = 0.0;
        #pragma unroll
        for (int k = 0; k < 16; ++k) if (i0 + k >= 1) np = fma(A[k], A[k], np);
        np += __shfl_xor(np, 1); np += __shfl_xor(np, 2);
        if (q == 0) nrmb[0] = np;
    }
    __syncthreads();

    // ---- factor: 64 Householder steps (LAPACK dlarfg signs), 1 barrier each --
    #pragma unroll 1
    for (int j = 0; j < 64; ++j) {
        const double* cbuf = colb[j & 1];
        const double alpha = cbuf[j];
        const double nrm2  = nrmb[j & 1];
        double beta, g;
        if (nrm2 == 0.0) { beta = alpha; g = 0.0; }          // H = I, tau = 0
        else {
            const double an = sqrt(fma(alpha, alpha, nrm2));
            beta = (alpha >= 0.0) ? -an : an;                // -sign(alpha)*norm
            g    = 1.0 / (beta * (beta - alpha));            // tau/(alpha-beta)^2
        }
        if (c >= j) {
            double cb[16];
            #pragma unroll
            for (int k = 0; k < 16; ++k) cb[k] = cbuf[i0 + k];
            double wp = 0.0, Ajc = 0.0;
            #pragma unroll
            for (int k = 0; k < 16; ++k) {
                const int i = i0 + k;
                wp  = fma((i > j) ? cb[k] : 0.0, A[k], wp);  // v0 (i>j) part
                Ajc += (i == j) ? A[k] : 0.0;                // A[j][c]
            }
            wp  += __shfl_xor(wp, 1);  wp  += __shfl_xor(wp, 2);
            Ajc += __shfl_xor(Ajc, 1); Ajc += __shfl_xor(Ajc, 2);
            const double amb = alpha - beta;
            const double gw  = g * (wp + amb * Ajc);         // g * v0^T A[:,c]
            #pragma unroll
            for (int k = 0; k < 16; ++k) {
                const int i = i0 + k;
                const double v0 = (i > j) ? cb[k] : ((i == j) ? amb : 0.0);
                A[k] = fma(-gw, v0, A[k]);
            }
            if (c == j + 1) {        // publish next column into the OTHER buffer
                #pragma unroll
                for (int k = 0; k < 16; ++k) colb[(j + 1) & 1][i0 + k] = A[k];
                double np = 0.0;
                #pragma unroll
                for (int k = 0; k < 16; ++k) {
                    const int i = i0 + k;
                    np = fma((i > j + 1) ? A[k] : 0.0, A[k], np);
                }
                np += __shfl_xor(np, 1); np += __shfl_xor(np, 2);
                if (q == 0) nrmb[(j + 1) & 1] = np;
            }
        }
        __syncthreads();
    }

    // ---- R to LDS, diag inverses/signs, qcol prologue ----
    #pragma unroll
    for (int k = 0; k < 16; ++k) Rs[(i0 + k) * 65 + c] = A[k];
    {
        double dv = 0.0;
        #pragma unroll
        for (int k = 0; k < 16; ++k) dv += (i0 + k == c) ? A[k] : 0.0;
        dv += __shfl_xor(dv, 1); dv += __shfl_xor(dv, 2);
        if (q == 0) dval[c] = dv;
    }
    if (c == 0) {
        #pragma unroll
        for (int k = 0; k < 16; ++k) qcol[0][i0 + k] = M[k];
    }
    __syncthreads();
    if (tid < 64) {
        const double d = dval[tid];
        dinv[tid] = 1.0 / d;
        const double NZL2E = 0.35355339059327373 * 1.4426950408889634; // 64^-.25*log2e
        sgnNZ[tid] = (d >= 0.0) ? NZL2E : -NZL2E;
    }
    __syncthreads();

    // ---- solve Q R = M (column sweep, 1 barrier/step); write P rows ----
    #pragma unroll 1
    for (int j = 0; j < 64; ++j) {
        const double fdi = dinv[j];
        if (c >= j) {
            const double* qc = qcol[j & 1];
            double qq[16];
            #pragma unroll
            for (int k = 0; k < 16; ++k) qq[k] = qc[i0 + k];
            if (c == j) {            // P[h][e=j][f] = Q[f][j]*sign(R[f][f])*NZL2E
                #pragma unroll
                for (int k = 0; k < 16; ++k)
                    P[h * 4096 + j * 64 + i0 + k] = (float)(qq[k] * fdi * sgnNZ[i0 + k]);
            } else {
                const double f = Rs[j * 65 + c] * fdi;
                #pragma unroll
                for (int k = 0; k < 16; ++k) M[k] = fma(-qq[k], f, M[k]);
                if (c == j + 1) {
                    #pragma unroll
                    for (int k = 0; k < 16; ++k) qcol[(j + 1) & 1][i0 + k] = M[k];
                }
            }
        }
        __syncthreads();
    }
}

// ---------------- FAVOR+ map: swizzled LDS tiles, wave-private, no barriers --
__global__ __launch_bounds__(256, 2) void favor_kernel(const float* __restrict__ data,
                                                       const float* __restrict__ P,
                                                       float* __restrict__ out)
{
    // single allocation: X dbuf 2x8192 floats + Ps 4096 floats = 81920 B
    __shared__ float SMEM[2 * 8192 + 4096];
    float* Ps = SMEM + 2 * 8192;

    const int tid   = threadIdx.x;
    const int h     = blockIdx.x & 15;
    const int chunk = blockIdx.x >> 4;              // 0..63
    const size_t rowbase = (size_t)chunk * 1024;    // 8 tiles x 128 rows

    const int lane = tid & 63;
    const int wv   = tid >> 6;
    const int rsub = lane >> 4;                     // row within 4-row group
    const int slot = lane & 15;                     // 16B slot this lane fills

    const float* db = data + (size_t)h * 64;

    // stage tile (wave-private rows 32*wv..32*wv+31): linear LDS dest,
    // XOR-pre-swizzled global source (chunk = slot ^ group_id&7)
#define STAGE(T, B) do {                                                          \
        const float* dr_ = db + (rowbase + (size_t)(T) * 128) * 1024;             \
        _Pragma("unroll")                                                         \
        for (int i_ = 0; i_ < 8; ++i_) {                                          \
            const int gidx_ = wv * 8 + i_;                                        \
            gload16(dr_ + (size_t)(gidx_ * 4 + rsub) * 1024 + ((slot ^ i_) << 2), \
                    SMEM + (B) * 8192 + gidx_ * 256);                             \
        }                                                                         \
    } while (0)

    STAGE(0, 0);
    #pragma unroll
    for (int k = 0; k < 4; ++k) {
        const int idx = tid + 256 * k;
        reinterpret_cast<float4*>(Ps)[idx] =
            reinterpret_cast<const float4*>(P)[h * 1024 + idx];
    }
    __syncthreads();                                // Ps visible; tile 0 landed

    const int fi = tid & 7;                         // features 8fi..8fi+7
    const int ri = tid >> 3;                        // rows 4ri..4ri+3 (own wave's)
    const float* pb = Ps + 8 * fi;
    const float SQS = 0.09016844005556021f;         // log2(e)/16
    float* ob = out + (size_t)h * 64 + 8 * fi;

#define FMA_J(ACC, XS, PA, PB, PC, PD) do {                                       \
        const f32x2 xx_ = {XS, XS};                                               \
        ACC[0] = fma2(xx_, PA, ACC[0]);                                           \
        ACC[1] = fma2(xx_, PB, ACC[1]);                                           \
        ACC[2] = fma2(xx_, PC, ACC[2]);                                           \
        ACC[3] = fma2(xx_, PD, ACC[3]);                                           \
    } while (0)

#define EPI(RR, ACC, SQ) do {                                                     \
        const float s_ = (SQ[0] + SQ[1]) * SQS;                                   \
        float4 oA_, oB_;                                                          \
        oA_.x = EXP2F(ACC[0][0] - s_) + 1e-6f;                                    \
        oA_.y = EXP2F(ACC[0][1] - s_) + 1e-6f;                                    \
        oA_.z = EXP2F(ACC[1][0] - s_) + 1e-6f;                                    \
        oA_.w = EXP2F(ACC[1][1] - s_) + 1e-6f;                                    \
        oB_.x = EXP2F(ACC[2][0] - s_) + 1e-6f;                                    \
        oB_.y = EXP2F(ACC[2][1] - s_) + 1e-6f;                                    \
        oB_.z = EXP2F(ACC[3][0] - s_) + 1e-6f;                                    \
        oB_.w = EXP2F(ACC[3][1] - s_) + 1e-6f;                                    \
        float* op_ = ob + (rowT + (size_t)(4 * ri + RR)) * 1024;                  \
        *reinterpret_cast<float4*>(op_)     = oA_;                                \
        *reinterpret_cast<float4*>(op_ + 4) = oB_;                                \
    } while (0)

    #pragma unroll 1
    for (int t = 0; t < 8; ++t) {
        if (t < 7) {
            asm volatile("s_waitcnt lgkmcnt(0)" ::: "memory");
            STAGE(t + 1, (t + 1) & 1);
            asm volatile("s_waitcnt vmcnt(8)" ::: "memory");  // tile t ready (wave-private)
        } else {
            asm volatile("s_waitcnt vmcnt(0)" ::: "memory");
        }
        const float* xb = SMEM + (t & 1) * 8192 + ri * 256;   // rows 4ri..4ri+3
        f32x2 a0[4], a1[4], a2[4], a3[4];
        #pragma unroll
        for (int k = 0; k < 4; ++k) {
            a0[k] = (f32x2){0.f, 0.f}; a1[k] = (f32x2){0.f, 0.f};
            a2[k] = (f32x2){0.f, 0.f}; a3[k] = (f32x2){0.f, 0.f};
        }
        f32x2 sq0 = {0.f, 0.f}, sq1 = {0.f, 0.f}, sq2 = {0.f, 0.f}, sq3 = {0.f, 0.f};

        #pragma unroll
        for (int eq = 0; eq < 16; ++eq) {
            const int sl4 = (eq ^ (ri & 7)) * 4;              // swizzled 16B slot
            const float4 xv0 = *reinterpret_cast<const float4*>(xb +       sl4);
            const float4 xv1 = *reinterpret_cast<const float4*>(xb +  64 + sl4);
            const float4 xv2 = *reinterpret_cast<const float4*>(xb + 128 + sl4);
            const float4 xv3 = *reinterpret_cast<const float4*>(xb + 192 + sl4);
            const float* x0 = reinterpret_cast<const float*>(&xv0);
            const float* x1 = reinterpret_cast<const float*>(&xv1);
            const float* x2 = reinterpret_cast<const float*>(&xv2);
            const float* x3 = reinterpret_cast<const float*>(&xv3);
            #pragma unroll
            for (int j = 0; j < 4; ++j) {
                const float4 plo = *reinterpret_cast<const float4*>(pb + (4 * eq + j) * 64);
                const float4 phi = *reinterpret_cast<const float4*>(pb + (4 * eq + j) * 64 + 4);
                const f32x2 pA = {plo.x, plo.y}, pB = {plo.z, plo.w};
                const f32x2 pC = {phi.x, phi.y}, pD = {phi.z, phi.w};
                FMA_J(a0, x0[j], pA, pB, pC, pD);
                FMA_J(a1, x1[j], pA, pB, pC, pD);
                FMA_J(a2, x2[j], pA, pB, pC, pD);
                FMA_J(a3, x3[j], pA, pB, pC, pD);
            }
            const f32x2 xl0 = {xv0.x, xv0.y}, xh0 = {xv0.z, xv0.w};
            const f32x2 xl1 = {xv1.x, xv1.y}, xh1 = {xv1.z, xv1.w};
            const f32x2 xl2 = {xv2.x, xv2.y}, xh2 = {xv2.z, xv2.w};
            const f32x2 xl3 = {xv3.x, xv3.y}, xh3 = {xv3.z, xv3.w};
            sq0 = fma2(xl0, xl0, sq0); sq0 = fma2(xh0, xh0, sq0);
            sq1 = fma2(xl1, xl1, sq1); sq1 = fma2(xh1, xh1, sq1);
            sq2 = fma2(xl2, xl2, sq2); sq2 = fma2(xh2, xh2, sq2);
            sq3 = fma2(xl3, xl3, sq3); sq3 = fma2(xh3, xh3, sq3);
        }
        const size_t rowT = rowbase + (size_t)t * 128;
        EPI(0, a0, sq0);
        EPI(1, a1, sq1);
        EPI(2, a2, sq2);
        EPI(3, a3, sq3);
    }
#undef STAGE
#undef FMA_J
#undef EPI
}

extern "C" void kernel_launch(void* const* d_in, const int* in_sizes, int n_in,
                              void* d_out, int out_size, void* d_ws, size_t ws_size,
                              hipStream_t stream)
{
    const float* data = (const float*)d_in[0];   // (L,N,H,E) fp32
    const float* pm   = (const float*)d_in[1];   // (H,E,E)   fp32
    float* out = (float*)d_out;                  // (L,N,H,F) fp32
    float* P   = (float*)d_ws;                   // 16*64*64*4 = 256 KB scratch

    qr_kernel<<<16, 256, 0, stream>>>(pm, P);
    favor_kernel<<<1024, 256, 0, stream>>>(data, P, out);
}

// Round 7
// 221.668 us; speedup vs baseline: 1.7918x; 1.1222x over previous
//
#include <hip/hip_runtime.h>
#include <math.h>

// L=4096, N=16, H=16, E=64. rho = L*N = 65536 rows of 1024 floats (head h at +64h).
// out[rho][h][f] = exp2( x.Ps[h][:,f] - sq*SQS ) + 1e-6, Ps = proj*64^-.25*log2e.
// proj = q^T D, D = sign(diag(r)) of LAPACK-convention QR(pm[h]^T) (convention-
// dependent — must reproduce geqrf signs). Factor then Q = M R^-1.
// favor: f16 hi/lo split MFMA (C = Xh(Bh+Bl) + Xl*Bh), residual ~2^-23 — the
// fp32 vector pipe (157 TF) was the round-6 limiter; MFMA moves the 4.3G-fma
// GEMM to the matrix pipe and leaves favor HBM-bound.

typedef _Float16 f16x8 __attribute__((ext_vector_type(8)));
typedef float    f32x4 __attribute__((ext_vector_type(4)));

#define AS1 __attribute__((address_space(1)))
#define AS3 __attribute__((address_space(3)))

#if __has_builtin(__builtin_amdgcn_exp2f)
#define EXP2F(x) __builtin_amdgcn_exp2f(x)
#else
#define EXP2F(x) exp2f(x)
#endif

static __device__ __forceinline__ void gload16(const float* g, float* l) {
    __builtin_amdgcn_global_load_lds((AS1 const void*)g, (AS3 void*)l, 16, 0, 0);
}

// ---------------- per-head QR: tid=4c+q, quad-shfl reduce, 1 barrier/step ----
__global__ __launch_bounds__(256) void qr_kernel(const float* __restrict__ pm,
                                                 float* __restrict__ P)
{
    __shared__ double colb[2][64];
    __shared__ double nrmb[2];
    __shared__ double Rs[64 * 65];
    __shared__ double qcol[2][64];
    __shared__ double dval[64];
    __shared__ double dinv[64];
    __shared__ double sgnNZ[64];

    const int tid = threadIdx.x;
    const int h   = blockIdx.x;
    const int c   = tid >> 2;       // column 0..63 (quad = 4 consecutive lanes)
    const int q   = tid & 3;        // row-quarter
    const int i0  = q * 16;

    double A[16], M[16];            // A[k] = M[i0+k][c] = pm[h][c][i0+k]
    {
        const float4* src = reinterpret_cast<const float4*>(pm + h * 4096 + c * 64 + i0);
        #pragma unroll
        for (int k4 = 0; k4 < 4; ++k4) {
            const float4 v = src[k4];
            A[4*k4+0] = M[4*k4+0] = (double)v.x;
            A[4*k4+1] = M[4*k4+1] = (double)v.y;
            A[4*k4+2] = M[4*k4+2] = (double)v.z;
            A[4*k4+3] = M[4*k4+3] = (double)v.w;
        }
    }
    if (c == 0) {                    // publish column 0 + its sub-norm
        #pragma unroll
        for (int k = 0; k < 16; ++k) colb[0][i0 + k] = A[k];
        double np = 0.0;
        #pragma unroll
        for (int k = 0; k < 16; ++k) if (i0 + k >= 1) np = fma(A[k], A[k], np);
        np += __shfl_xor(np, 1); np += __shfl_xor(np, 2);
        if (q == 0) nrmb[0] = np;
    }
    __syncthreads();

    // ---- factor: 64 Householder steps (LAPACK dlarfg signs), 1 barrier each --
    #pragma unroll 1
    for (int j = 0; j < 64; ++j) {
        const double* cbuf = colb[j & 1];
        const double alpha = cbuf[j];
        const double nrm2  = nrmb[j & 1];
        double beta, g;
        if (nrm2 == 0.0) { beta = alpha; g = 0.0; }          // H = I, tau = 0
        else {
            const double an = sqrt(fma(alpha, alpha, nrm2));
            beta = (alpha >= 0.0) ? -an : an;                // -sign(alpha)*norm
            g    = 1.0 / (beta * (beta - alpha));            // tau/(alpha-beta)^2
        }
        if (c >= j) {
            double cb[16];
            #pragma unroll
            for (int k = 0; k < 16; ++k) cb[k] = cbuf[i0 + k];
            double wp = 0.0, Ajc = 0.0;
            #pragma unroll
            for (int k = 0; k < 16; ++k) {
                const int i = i0 + k;
                wp  = fma((i > j) ? cb[k] : 0.0, A[k], wp);  // v0 (i>j) part
                Ajc += (i == j) ? A[k] : 0.0;                // A[j][c]
            }
            wp  += __shfl_xor(wp, 1);  wp  += __shfl_xor(wp, 2);
            Ajc += __shfl_xor(Ajc, 1); Ajc += __shfl_xor(Ajc, 2);
            const double amb = alpha - beta;
            const double gw  = g * (wp + amb * Ajc);         // g * v0^T A[:,c]
            #pragma unroll
            for (int k = 0; k < 16; ++k) {
                const int i = i0 + k;
                const double v0 = (i > j) ? cb[k] : ((i == j) ? amb : 0.0);
                A[k] = fma(-gw, v0, A[k]);
            }
            if (c == j + 1) {        // publish next column into the OTHER buffer
                #pragma unroll
                for (int k = 0; k < 16; ++k) colb[(j + 1) & 1][i0 + k] = A[k];
                double np = 0.0;
                #pragma unroll
                for (int k = 0; k < 16; ++k) {
                    const int i = i0 + k;
                    np = fma((i > j + 1) ? A[k] : 0.0, A[k], np);
                }
                np += __shfl_xor(np, 1); np += __shfl_xor(np, 2);
                if (q == 0) nrmb[(j + 1) & 1] = np;
            }
        }
        __syncthreads();
    }

    // ---- R to LDS, diag inverses/signs, qcol prologue ----
    #pragma unroll
    for (int k = 0; k < 16; ++k) Rs[(i0 + k) * 65 + c] = A[k];
    {
        double dv = 0.0;
        #pragma unroll
        for (int k = 0; k < 16; ++k) dv += (i0 + k == c) ? A[k] : 0.0;
        dv += __shfl_xor(dv, 1); dv += __shfl_xor(dv, 2);
        if (q == 0) dval[c] = dv;
    }
    if (c == 0) {
        #pragma unroll
        for (int k = 0; k < 16; ++k) qcol[0][i0 + k] = M[k];
    }
    __syncthreads();
    if (tid < 64) {
        const double d = dval[tid];
        dinv[tid] = 1.0 / d;
        const double NZL2E = 0.35355339059327373 * 1.4426950408889634; // 64^-.25*log2e
        sgnNZ[tid] = (d >= 0.0) ? NZL2E : -NZL2E;
    }
    __syncthreads();

    // ---- solve Q R = M (column sweep, 1 barrier/step); write P rows ----
    #pragma unroll 1
    for (int j = 0; j < 64; ++j) {
        const double fdi = dinv[j];
        if (c >= j) {
            const double* qc = qcol[j & 1];
            double qq[16];
            #pragma unroll
            for (int k = 0; k < 16; ++k) qq[k] = qc[i0 + k];
            if (c == j) {            // P[h][e=j][f] = Q[f][j]*sign(R[f][f])*NZL2E
                #pragma unroll
                for (int k = 0; k < 16; ++k)
                    P[h * 4096 + j * 64 + i0 + k] = (float)(qq[k] * fdi * sgnNZ[i0 + k]);
            } else {
                const double f = Rs[j * 65 + c] * fdi;
                #pragma unroll
                for (int k = 0; k < 16; ++k) M[k] = fma(-qq[k], f, M[k]);
                if (c == j + 1) {
                    #pragma unroll
                    for (int k = 0; k < 16; ++k) qcol[(j + 1) & 1][i0 + k] = M[k];
                }
            }
        }
        __syncthreads();
    }
}

// ---------------- FAVOR+ map: f16-split MFMA, wave-private staging ----------
__global__ __launch_bounds__(256, 2) void favor_kernel(const float* __restrict__ data,
                                                       const float* __restrict__ P,
                                                       float* __restrict__ out)
{
    // X dbuf 2x8192 floats (swizzled rows of 64) + Ps 4096 floats = 80 KB
    __shared__ float SMEM[2 * 8192 + 4096];
    float* Ps = SMEM + 16384;

    const int tid   = threadIdx.x;
    const int h     = blockIdx.x & 15;
    const int chunk = blockIdx.x >> 4;              // 0..63
    const size_t rowbase = (size_t)chunk * 1024;    // 8 tiles x 128 rows

    const int lane = tid & 63;
    const int wv   = tid >> 6;                      // wave owns rows 32wv..32wv+31
    const int ls   = lane & 15;                     // slot / A-row / B-col / C-col
    const int lg   = lane >> 4;                     // k-group / stage row-sub

    const float* db = data + (size_t)h * 64;

    // stage: linear LDS dest (gload_lds), XOR-pre-swizzled global source so that
    // row r's logical 16B slot s lands at phys slot s^(r&15)  [rule 21]
#define STAGE(T, B) do {                                                           \
        const size_t rT_ = rowbase + (size_t)(T) * 128 + 32 * wv;                  \
        float* dst_ = SMEM + (B) * 8192 + wv * 2048;                               \
        _Pragma("unroll")                                                          \
        for (int i_ = 0; i_ < 8; ++i_) {                                           \
            const int rl_ = 4 * i_ + lg;                                           \
            gload16(db + (rT_ + (size_t)rl_) * 1024 + ((ls ^ (rl_ & 15)) << 2),    \
                    dst_ + i_ * 256);                                              \
        }                                                                          \
    } while (0)

    STAGE(0, 0);
    #pragma unroll
    for (int k = 0; k < 4; ++k) {
        const int idx = tid + 256 * k;
        reinterpret_cast<float4*>(Ps)[idx] =
            reinterpret_cast<const float4*>(P)[h * 1024 + idx];
    }
    __syncthreads();     // Ps visible to all waves (also drains tile-0 loads)

    // B fragments: f16 hi/lo split of Ps, resident in registers.
    // B[k][col]: col = n*16 + ls, k = kh*32 + lg*8 + j
    f16x8 bh[4][2], bl[4][2];
    #pragma unroll
    for (int n = 0; n < 4; ++n) {
        #pragma unroll
        for (int kh = 0; kh < 2; ++kh) {
            #pragma unroll
            for (int j = 0; j < 8; ++j) {
                const int kk = kh * 32 + lg * 8 + j;
                const float pv = Ps[kk * 64 + n * 16 + ls];
                const _Float16 hi = (_Float16)pv;
                bh[n][kh][j] = hi;
                bl[n][kh][j] = (_Float16)(pv - (float)hi);
            }
        }
    }

    const float SQS = 0.09016844005556021f;          // log2(e)/16
    #pragma unroll 1
    for (int t = 0; t < 8; ++t) {
        if (t < 7) {
            asm volatile("s_waitcnt lgkmcnt(0)" ::: "memory");  // prior-tile reads retired
            STAGE(t + 1, (t + 1) & 1);
            asm volatile("s_waitcnt vmcnt(8)" ::: "memory");    // tile t landed
        } else {
            asm volatile("s_waitcnt vmcnt(0)" ::: "memory");
        }
        const float* xb = SMEM + (t & 1) * 8192 + wv * 2048;

        // ---- A fragments (f16 hi/lo) + row sum-of-squares ----
        f16x8 ah[2][2], al[2][2];                    // [mtile][khalf]
        float sqv[2];
        #pragma unroll
        for (int mt = 0; mt < 2; ++mt) {
            const float* xr = xb + (16 * mt + ls) * 64;   // A-row = 16mt + ls
            float sq = 0.f;
            #pragma unroll
            for (int kh = 0; kh < 2; ++kh) {
                const int s0 = (8 * kh + 2 * lg) ^ ls;    // swizzled 16B slots
                const int s1 = (8 * kh + 2 * lg + 1) ^ ls;
                const float4 va = *reinterpret_cast<const float4*>(xr + 4 * s0);
                const float4 vb = *reinterpret_cast<const float4*>(xr + 4 * s1);
                const float xs[8] = {va.x, va.y, va.z, va.w, vb.x, vb.y, vb.z, vb.w};
                #pragma unroll
                for (int j = 0; j < 8; ++j) {
                    const float xv = xs[j];
                    const _Float16 hi = (_Float16)xv;
                    ah[mt][kh][j] = hi;
                    al[mt][kh][j] = (_Float16)(xv - (float)hi);
                    sq = fmaf(xv, xv, sq);
                }
            }
            sq += __shfl_xor(sq, 16);                 // complete the 64-k sum
            sq += __shfl_xor(sq, 32);
            sqv[mt] = sq;                             // valid for row 16mt + ls
        }

        // ---- 48 MFMAs: C = Xh*Bh + Xh*Bl + Xl*Bh ----
        f32x4 acc[2][4];
        #pragma unroll
        for (int mt = 0; mt < 2; ++mt) {
            #pragma unroll
            for (int n = 0; n < 4; ++n) {
                f32x4 a = {0.f, 0.f, 0.f, 0.f};
                #pragma unroll
                for (int kh = 0; kh < 2; ++kh) {
                    a = __builtin_amdgcn_mfma_f32_16x16x32_f16(ah[mt][kh], bh[n][kh], a, 0, 0, 0);
                    a = __builtin_amdgcn_mfma_f32_16x16x32_f16(ah[mt][kh], bl[n][kh], a, 0, 0, 0);
                    a = __builtin_amdgcn_mfma_f32_16x16x32_f16(al[mt][kh], bh[n][kh], a, 0, 0, 0);
                }
                acc[mt][n] = a;
            }
        }

        // ---- epilogue: C[row=4lg+reg][col=16n+ls], exp2 + eps, scalar stores --
        const size_t rowT = rowbase + (size_t)t * 128 + 32 * wv;
        #pragma unroll
        for (int mt = 0; mt < 2; ++mt) {
            #pragma unroll
            for (int reg = 0; reg < 4; ++reg) {
                const int row_i = 4 * lg + reg;
                const float sqr = __shfl(sqv[mt], row_i) * SQS;  // from lane row_i
                float* orow = out + (rowT + (size_t)(16 * mt + row_i)) * 1024
                                  + (size_t)h * 64 + ls;
                #pragma unroll
                for (int n = 0; n < 4; ++n)
                    orow[16 * n] = EXP2F(acc[mt][n][reg] - sqr) + 1e-6f;
            }
        }
    }
#undef STAGE
}

extern "C" void kernel_launch(void* const* d_in, const int* in_sizes, int n_in,
                              void* d_out, int out_size, void* d_ws, size_t ws_size,
                              hipStream_t stream)
{
    const float* data = (const float*)d_in[0];   // (L,N,H,E) fp32
    const float* pm   = (const float*)d_in[1];   // (H,E,E)   fp32
    float* out = (float*)d_out;                  // (L,N,H,F) fp32
    float* P   = (float*)d_ws;                   // 16*64*64*4 = 256 KB scratch

    qr_kernel<<<16, 256, 0, stream>>>(pm, P);
    favor_kernel<<<1024, 256, 0, stream>>>(data, P, out);
}

// Round 8
// 191.207 us; speedup vs baseline: 2.0772x; 1.1593x over previous
//
#include <hip/hip_runtime.h>
#include <math.h>

// L=4096, N=16, H=16, E=64. rho = L*N = 65536 rows of 1024 floats (head h at +64h).
// out[rho][h][f] = exp2( x.Ps[h][:,f] - sq*SQS ) + 1e-6, Ps = proj*64^-.25*log2e.
// proj = q^T D, D = sign(diag(r)) of LAPACK-convention QR(pm[h]^T) (convention-
// dependent — must reproduce geqrf signs). Factor then Q = M R^-1.
// favor: f16 hi/lo split MFMA (C = Xh*Bh + Xh*Bl + Xl*Bh), residual ~2^-23.
// Counted vmcnt: stores stay in flight across tiles (vmcnt(40) allows
// stores(t-1)[32] + loads(t+1)[8]; in-order counting retires loads(t) exactly).

typedef _Float16 f16x8 __attribute__((ext_vector_type(8)));
typedef float    f32x4 __attribute__((ext_vector_type(4)));

#define AS1 __attribute__((address_space(1)))
#define AS3 __attribute__((address_space(3)))

#if __has_builtin(__builtin_amdgcn_exp2f)
#define EXP2F(x) __builtin_amdgcn_exp2f(x)
#else
#define EXP2F(x) exp2f(x)
#endif

static __device__ __forceinline__ void gload16(const float* g, float* l) {
    __builtin_amdgcn_global_load_lds((AS1 const void*)g, (AS3 void*)l, 16, 0, 0);
}

// ---------------- per-head QR (fp32 Householder, LAPACK dlarfg signs) -------
// Backward-stable in fp32 (err ~ n*eps ~ 4e-6 rel); tid = 4c+q, quad-shfl
// reductions, 1 barrier/step factor + 1 barrier/step solve.
__global__ __launch_bounds__(256) void qr_kernel(const float* __restrict__ pm,
                                                 float* __restrict__ P)
{
    __shared__ float colb[2][64];
    __shared__ float nrmb[2];
    __shared__ float Rs[64 * 65];
    __shared__ float qcol[2][64];
    __shared__ float dval[64];
    __shared__ float dinv[64];
    __shared__ float sgnNZ[64];

    const int tid = threadIdx.x;
    const int h   = blockIdx.x;
    const int c   = tid >> 2;       // column 0..63 (quad = 4 consecutive lanes)
    const int q   = tid & 3;        // row-quarter
    const int i0  = q * 16;

    float A[16], M[16];             // A[k] = M[i0+k][c] = pm[h][c][i0+k]
    {
        const float4* src = reinterpret_cast<const float4*>(pm + h * 4096 + c * 64 + i0);
        #pragma unroll
        for (int k4 = 0; k4 < 4; ++k4) {
            const float4 v = src[k4];
            A[4*k4+0] = M[4*k4+0] = v.x;
            A[4*k4+1] = M[4*k4+1] = v.y;
            A[4*k4+2] = M[4*k4+2] = v.z;
            A[4*k4+3] = M[4*k4+3] = v.w;
        }
    }
    if (c == 0) {                    // publish column 0 + its sub-norm
        #pragma unroll
        for (int k = 0; k < 16; ++k) colb[0][i0 + k] = A[k];
        float np = 0.f;
        #pragma unroll
        for (int k = 0; k < 16; ++k) if (i0 + k >= 1) np = fmaf(A[k], A[k], np);
        np += __shfl_xor(np, 1); np += __shfl_xor(np, 2);
        if (q == 0) nrmb[0] = np;
    }
    __syncthreads();

    // ---- factor: 64 Householder steps, 1 barrier each ----
    #pragma unroll 1
    for (int j = 0; j < 64; ++j) {
        const float* cbuf = colb[j & 1];
        const float alpha = cbuf[j];
        const float nrm2  = nrmb[j & 1];
        float beta, g;
        if (nrm2 == 0.f) { beta = alpha; g = 0.f; }          // H = I, tau = 0
        else {
            const float an = sqrtf(fmaf(alpha, alpha, nrm2));
            beta = (alpha >= 0.f) ? -an : an;                // -sign(alpha)*norm
            g    = 1.f / (beta * (beta - alpha));            // tau/(alpha-beta)^2
        }
        if (c >= j) {
            float cb[16];
            #pragma unroll
            for (int k = 0; k < 16; ++k) cb[k] = cbuf[i0 + k];
            float wp = 0.f, Ajc = 0.f;
            #pragma unroll
            for (int k = 0; k < 16; ++k) {
                const int i = i0 + k;
                wp  = fmaf((i > j) ? cb[k] : 0.f, A[k], wp); // v0 (i>j) part
                Ajc += (i == j) ? A[k] : 0.f;                // A[j][c]
            }
            wp  += __shfl_xor(wp, 1);  wp  += __shfl_xor(wp, 2);
            Ajc += __shfl_xor(Ajc, 1); Ajc += __shfl_xor(Ajc, 2);
            const float amb = alpha - beta;
            const float gw  = g * (wp + amb * Ajc);          // g * v0^T A[:,c]
            #pragma unroll
            for (int k = 0; k < 16; ++k) {
                const int i = i0 + k;
                const float v0 = (i > j) ? cb[k] : ((i == j) ? amb : 0.f);
                A[k] = fmaf(-gw, v0, A[k]);
            }
            if (c == j + 1) {        // publish next column into the OTHER buffer
                #pragma unroll
                for (int k = 0; k < 16; ++k) colb[(j + 1) & 1][i0 + k] = A[k];
                float np = 0.f;
                #pragma unroll
                for (int k = 0; k < 16; ++k) {
                    const int i = i0 + k;
                    np = fmaf((i > j + 1) ? A[k] : 0.f, A[k], np);
                }
                np += __shfl_xor(np, 1); np += __shfl_xor(np, 2);
                if (q == 0) nrmb[(j + 1) & 1] = np;
            }
        }
        __syncthreads();
    }

    // ---- R to LDS, diag inverses/signs, qcol prologue ----
    #pragma unroll
    for (int k = 0; k < 16; ++k) Rs[(i0 + k) * 65 + c] = A[k];
    {
        float dv = 0.f;
        #pragma unroll
        for (int k = 0; k < 16; ++k) dv += (i0 + k == c) ? A[k] : 0.f;
        dv += __shfl_xor(dv, 1); dv += __shfl_xor(dv, 2);
        if (q == 0) dval[c] = dv;
    }
    if (c == 0) {
        #pragma unroll
        for (int k = 0; k < 16; ++k) qcol[0][i0 + k] = M[k];
    }
    __syncthreads();
    if (tid < 64) {
        const float d = dval[tid];
        dinv[tid] = 1.f / d;
        const float NZL2E = 0.51012934f;     // 64^-0.25 * log2(e)
        sgnNZ[tid] = (d >= 0.f) ? NZL2E : -NZL2E;
    }
    __syncthreads();

    // ---- solve Q R = M (column sweep, 1 barrier/step); write P rows ----
    #pragma unroll 1
    for (int j = 0; j < 64; ++j) {
        const float fdi = dinv[j];
        if (c >= j) {
            const float* qc = qcol[j & 1];
            float qq[16];
            #pragma unroll
            for (int k = 0; k < 16; ++k) qq[k] = qc[i0 + k];
            if (c == j) {            // P[h][e=j][f] = Q[f][j]*sign(R[f][f])*NZL2E
                #pragma unroll
                for (int k = 0; k < 16; ++k)
                    P[h * 4096 + j * 64 + i0 + k] = qq[k] * fdi * sgnNZ[i0 + k];
            } else {
                const float f = Rs[j * 65 + c] * fdi;
                #pragma unroll
                for (int k = 0; k < 16; ++k) M[k] = fmaf(-qq[k], f, M[k]);
                if (c == j + 1) {
                    #pragma unroll
                    for (int k = 0; k < 16; ++k) qcol[(j + 1) & 1][i0 + k] = M[k];
                }
            }
        }
        __syncthreads();
    }
}

// ---------------- FAVOR+ map: f16-split MFMA, wave-private staging ----------
__global__ __launch_bounds__(256, 2) void favor_kernel(const float* __restrict__ data,
                                                       const float* __restrict__ P,
                                                       float* __restrict__ out)
{
    // X dbuf 2x8192 floats (swizzled rows of 64) + Ps 4096 floats = 80 KB
    __shared__ float SMEM[2 * 8192 + 4096];
    float* Ps = SMEM + 16384;

    const int tid   = threadIdx.x;
    const int h     = blockIdx.x & 15;
    const int chunk = blockIdx.x >> 4;              // 0..63
    const size_t rowbase = (size_t)chunk * 1024;    // 8 tiles x 128 rows

    const int lane = tid & 63;
    const int wv   = tid >> 6;                      // wave owns rows 32wv..32wv+31
    const int ls   = lane & 15;                     // slot / A-row / B-col / C-col
    const int lg   = lane >> 4;                     // k-group / stage row-sub

    const float* db = data + (size_t)h * 64;

    // stage: linear LDS dest (gload_lds), XOR-pre-swizzled global source so that
    // row r's logical 16B slot s lands at phys slot s^(r&15)  [rule 21]
#define STAGE(T, B) do {                                                           \
        const size_t rT_ = rowbase + (size_t)(T) * 128 + 32 * wv;                  \
        float* dst_ = SMEM + (B) * 8192 + wv * 2048;                               \
        _Pragma("unroll")                                                          \
        for (int i_ = 0; i_ < 8; ++i_) {                                           \
            const int rl_ = 4 * i_ + lg;                                           \
            gload16(db + (rT_ + (size_t)rl_) * 1024 + ((ls ^ (rl_ & 15)) << 2),    \
                    dst_ + i_ * 256);                                              \
        }                                                                          \
    } while (0)

    // P loads first (oldest in vmcnt order), then tile-0 prefetch: the Ps-use
    // wait then drains only the P loads, leaving the prefetch in flight.
    float4 preg[4];
    #pragma unroll
    for (int k = 0; k < 4; ++k)
        preg[k] = reinterpret_cast<const float4*>(P)[h * 1024 + tid + 256 * k];
    STAGE(0, 0);
    #pragma unroll
    for (int k = 0; k < 4; ++k)
        reinterpret_cast<float4*>(Ps)[tid + 256 * k] = preg[k];
    __syncthreads();     // Ps visible to all waves

    // B fragments: f16 hi/lo split of Ps, resident in registers.
    // B[k][col]: col = n*16 + ls, k = kh*32 + lg*8 + j
    f16x8 bh[4][2], bl[4][2];
    #pragma unroll
    for (int n = 0; n < 4; ++n) {
        #pragma unroll
        for (int kh = 0; kh < 2; ++kh) {
            #pragma unroll
            for (int j = 0; j < 8; ++j) {
                const int kk = kh * 32 + lg * 8 + j;
                const float pv = Ps[kk * 64 + n * 16 + ls];
                const _Float16 hi = (_Float16)pv;
                bh[n][kh][j] = hi;
                bl[n][kh][j] = (_Float16)(pv - (float)hi);
            }
        }
    }

    const float SQS = 0.09016844005556021f;          // log2(e)/16
    #pragma unroll 1
    for (int t = 0; t < 8; ++t) {
        if (t < 7) {
            asm volatile("s_waitcnt lgkmcnt(0)" ::: "memory");  // prior reads retired
            STAGE(t + 1, (t + 1) & 1);
        }
        // In-order vmcnt: retire tile-t loads, leave epilogue stores in flight.
        if (t == 0)      asm volatile("s_waitcnt vmcnt(8)"  ::: "memory");
        else if (t < 7)  asm volatile("s_waitcnt vmcnt(40)" ::: "memory");
        else             asm volatile("s_waitcnt vmcnt(32)" ::: "memory");

        const float* xb = SMEM + (t & 1) * 8192 + wv * 2048;

        // ---- A fragments (f16 hi/lo) + row sum-of-squares ----
        f16x8 ah[2][2], al[2][2];                    // [mtile][khalf]
        float sqv[2];
        #pragma unroll
        for (int mt = 0; mt < 2; ++mt) {
            const float* xr = xb + (16 * mt + ls) * 64;   // A-row = 16mt + ls
            float sq = 0.f;
            #pragma unroll
            for (int kh = 0; kh < 2; ++kh) {
                const int s0 = (8 * kh + 2 * lg) ^ ls;    // swizzled 16B slots
                const int s1 = (8 * kh + 2 * lg + 1) ^ ls;
                const float4 va = *reinterpret_cast<const float4*>(xr + 4 * s0);
                const float4 vb = *reinterpret_cast<const float4*>(xr + 4 * s1);
                const float xs[8] = {va.x, va.y, va.z, va.w, vb.x, vb.y, vb.z, vb.w};
                #pragma unroll
                for (int j = 0; j < 8; ++j) {
                    const float xv = xs[j];
                    const _Float16 hi = (_Float16)xv;
                    ah[mt][kh][j] = hi;
                    al[mt][kh][j] = (_Float16)(xv - (float)hi);
                    sq = fmaf(xv, xv, sq);
                }
            }
            sq += __shfl_xor(sq, 16);                 // complete the 64-k sum
            sq += __shfl_xor(sq, 32);
            sqv[mt] = sq;                             // valid for row 16mt + ls
        }

        // ---- 48 MFMAs: C = Xh*Bh + Xh*Bl + Xl*Bh ----
        f32x4 acc[2][4];
        #pragma unroll
        for (int mt = 0; mt < 2; ++mt) {
            #pragma unroll
            for (int n = 0; n < 4; ++n) {
                f32x4 a = {0.f, 0.f, 0.f, 0.f};
                #pragma unroll
                for (int kh = 0; kh < 2; ++kh) {
                    a = __builtin_amdgcn_mfma_f32_16x16x32_f16(ah[mt][kh], bh[n][kh], a, 0, 0, 0);
                    a = __builtin_amdgcn_mfma_f32_16x16x32_f16(ah[mt][kh], bl[n][kh], a, 0, 0, 0);
                    a = __builtin_amdgcn_mfma_f32_16x16x32_f16(al[mt][kh], bh[n][kh], a, 0, 0, 0);
                }
                acc[mt][n] = a;
            }
        }

        // ---- epilogue: C[row=4lg+reg][col=16n+ls], exp2 + eps, scalar stores --
        const size_t rowT = rowbase + (size_t)t * 128 + 32 * wv;
        #pragma unroll
        for (int mt = 0; mt < 2; ++mt) {
            #pragma unroll
            for (int reg = 0; reg < 4; ++reg) {
                const int row_i = 4 * lg + reg;
                const float sqr = __shfl(sqv[mt], row_i) * SQS;  // from lane row_i
                float* orow = out + (rowT + (size_t)(16 * mt + row_i)) * 1024
                                  + (size_t)h * 64 + ls;
                #pragma unroll
                for (int n = 0; n < 4; ++n)
                    orow[16 * n] = EXP2F(acc[mt][n][reg] - sqr) + 1e-6f;
            }
        }
    }
#undef STAGE
}

extern "C" void kernel_launch(void* const* d_in, const int* in_sizes, int n_in,
                              void* d_out, int out_size, void* d_ws, size_t ws_size,
                              hipStream_t stream)
{
    const float* data = (const float*)d_in[0];   // (L,N,H,E) fp32
    const float* pm   = (const float*)d_in[1];   // (H,E,E)   fp32
    float* out = (float*)d_out;                  // (L,N,H,F) fp32
    float* P   = (float*)d_ws;                   // 16*64*64*4 = 256 KB scratch

    qr_kernel<<<16, 256, 0, stream>>>(pm, P);
    favor_kernel<<<1024, 256, 0, stream>>>(data, P, out);
}